// Round 3
// baseline (258.038 us; speedup 1.0000x reference)
//
#include <hip/hip_runtime.h>

// DropNorm: B=4096 rows, F=8192 features, fp32.
//   n = F/2; mu = sum(x*m)/n; sigma2 = sum(((x-mu)*m)^2)/(n-1)
//   out = gamma*m*(x-mu)*rsqrt(sigma2^2 + 1e-4) + beta   [sigma2 SQUARED: quirk]
//
// R6 = R5 resubmitted (round-2 bench died with "MI355X container failed
// twice" — infra, no measurement; kernel re-audited, no OOB/misalignment/
// divergent-shuffle hazards found; do not mutate hypothesis on infra failure).
//
// R5 rationale: wave-per-row, zero-barrier, two streaming sweeps.
//   R4 post-mortem: VGPR_Count=56 proved the compiler sank gv/bv loads past
//   the barrier (it minimizes regs, not MLP); dropnorm ran 79us @ 2.55 TB/s
//   while the harness fills hit 6.7 TB/s at 9.7% occupancy -> bandwidth comes
//   from CONTINUOUS per-wave streams, not occupancy. Block-per-row phases
//   (read burst -> barrier -> L2+store burst) leave vmem idle ~half the time.
//   Fix: each 64-lane wave owns one row (128 f32/lane).
//     sweep1: 32 dwordx4/lane, double-buffered batches of 8 (16KB/wave in
//             flight), mask via per-lane packed uint4 bits, butterfly
//             __shfl_xor reduce. No LDS, no __syncthreads, waves independent.
//     sweep2: re-read row (L2/L3-hot: x fits 256MB L3), mg/beta from L2,
//             nontemporal store. Write stream never stalls.

constexpr int Bn = 4096;
constexpr int Fn = 8192;
constexpr int NT = 256;           // threads per block
constexpr int RPB = 4;            // rows per block (= waves per block)

typedef float f4 __attribute__((ext_vector_type(4)));

#define EPSV 1e-4f

__device__ inline int nzbytes(unsigned v) {
    return ((v & 0x000000ffu) != 0) + ((v & 0x0000ff00u) != 0) +
           ((v & 0x00ff0000u) != 0) + ((v & 0xff000000u) != 0);
}

// Prep: detect mask storage layout (uint8 bool vs int32), then materialize
//   mg[j]     = mask ? gamma[j] : 0.0                       (Fn floats)
//   lwpk[256] = per-lane packed mask bits for the main kernel:
//       uint4 word q of lane L, bit (4*(k&7)+j)  = mask[4*L + 256*k + j]
//       (feature of lane L, f4-chunk k, component j; k = 8q..8q+7)
// Detection: count nonzero among the first Fn BYTES. uint8 layout -> exactly
// Fn/2 = 4096; int32 layout -> those bytes span only 2048 ints -> count <= 2048.
__global__ __launch_bounds__(NT) void prep_kernel(const void* __restrict__ mask_raw,
                                                  const float* __restrict__ gamma,
                                                  unsigned* __restrict__ lwpk,
                                                  float* __restrict__ mg) {
    const unsigned char* mb = (const unsigned char*)mask_raw;
    const int* mi = (const int*)mask_raw;
    const uint4* mv = (const uint4*)mask_raw;
    const int tid = threadIdx.x;

    // vectorized nonzero-byte count over the first Fn bytes (512 uint4)
    int cnt = 0;
#pragma unroll
    for (int k = 0; k < Fn / 16 / NT; ++k) {   // 2 iterations
        const uint4 w = mv[tid + k * NT];
        cnt += nzbytes(w.x) + nzbytes(w.y) + nzbytes(w.z) + nzbytes(w.w);
    }
    for (int off = 32; off > 0; off >>= 1) cnt += __shfl_down(cnt, off, 64);

    __shared__ int wc[NT / 64];
    __shared__ int flag;
    if ((tid & 63) == 0) wc[tid >> 6] = cnt;
    __syncthreads();
    if (tid == 0) {
        int total = wc[0] + wc[1] + wc[2] + wc[3];
        flag = (total == Fn / 2) ? 1 : 0;   // 1 = uint8 layout, 0 = int32 layout
    }
    __syncthreads();
    const bool u8 = (flag != 0);

    // mg slice for this block
    const int per_block = Fn / gridDim.x;
    const int base = blockIdx.x * per_block;
    for (int j = base + tid; j < base + per_block; j += NT) {
        const bool on = u8 ? (mb[j] != 0) : (mi[j] != 0);
        mg[j] = on ? gamma[j] : 0.0f;
    }

    // packed per-lane mask words (block 0 only; mask bytes are cache-hot).
    // thread t builds word t: lane = t>>2, q = t&3.
    if (blockIdx.x == 0) {
        const int lane = tid >> 2;
        const int q = tid & 3;
        unsigned w = 0;
#pragma unroll
        for (int b = 0; b < 32; ++b) {
            const int k = 8 * q + (b >> 2);
            const int j = b & 3;
            const int f = 4 * lane + 256 * k + j;
            const bool on = u8 ? (mb[f] != 0) : (mi[f] != 0);
            w |= (on ? 1u : 0u) << b;
        }
        lwpk[tid] = w;
    }
}

__global__ __launch_bounds__(NT) void dropnorm_kernel(const float* __restrict__ x,
                                                      const unsigned* __restrict__ lwpk,
                                                      const float* __restrict__ mg,
                                                      const float* __restrict__ beta,
                                                      float* __restrict__ out) {
    const int tid = threadIdx.x;
    const int lane = tid & 63;
    const int row = blockIdx.x * RPB + (tid >> 6);

    const f4* __restrict__ xr = (const f4*)(x + (size_t)row * Fn);
    const f4* __restrict__ g4 = (const f4*)mg;
    const f4* __restrict__ b4 = (const f4*)beta;
    f4* __restrict__ o4       = (f4*)(out + (size_t)row * Fn);

    // one 16B load covers the mask for all 128 features this lane owns
    const uint4 lw = ((const uint4*)lwpk)[lane];

    // ---- sweep 1: masked accumulate over 32 f4-chunks, double-buffered x8.
    // 16 dwordx4 (16 KB/wave) in flight continuously; no barrier anywhere.
    float s = 0.f, ss = 0.f;
    f4 xb[2][8];
#pragma unroll
    for (int k = 0; k < 8; ++k) xb[0][k] = xr[lane + 64 * k];
#pragma unroll
    for (int q = 0; q < 4; ++q) {
        if (q < 3) {
#pragma unroll
            for (int k = 0; k < 8; ++k)
                xb[(q + 1) & 1][k] = xr[lane + 64 * ((q + 1) * 8 + k)];
        }
        const unsigned wq = (q == 0) ? lw.x : (q == 1) ? lw.y : (q == 2) ? lw.z : lw.w;
#pragma unroll
        for (int k = 0; k < 8; ++k) {
            const f4 v = xb[q & 1][k];
            const float a0 = ((wq >> (4 * k + 0)) & 1u) ? v.x : 0.f;
            const float a1 = ((wq >> (4 * k + 1)) & 1u) ? v.y : 0.f;
            const float a2 = ((wq >> (4 * k + 2)) & 1u) ? v.z : 0.f;
            const float a3 = ((wq >> (4 * k + 3)) & 1u) ? v.w : 0.f;
            s  += (a0 + a1) + (a2 + a3);
            ss += (a0 * a0 + a1 * a1) + (a2 * a2 + a3 * a3);
        }
    }

    // 64-lane butterfly: every lane ends up with the full row sums.
    for (int off = 32; off > 0; off >>= 1) {
        s  += __shfl_xor(s, off, 64);
        ss += __shfl_xor(ss, off, 64);
    }

    const float n  = (float)(Fn / 2);
    const float mu = s / n;
    // sum(diff^2) = sum(x^2 m) - n*mu^2   (sum(m) == n exactly)
    const float sigma2 = (ss - n * mu * mu) / (n - 1.0f);
    const float inv = rsqrtf(sigma2 * sigma2 + EPSV);  // quirk: sigma2 squared

    // ---- sweep 2: re-read row (L2/L3-hot) + mg/beta (L2-hot), apply, store.
    // masked-off features: mg==0 -> out = beta (matches scatter-into-zeros).
#pragma unroll
    for (int q = 0; q < 4; ++q) {
        f4 xv[8], gv[8], bv[8];
#pragma unroll
        for (int k = 0; k < 8; ++k) xv[k] = xr[lane + 64 * (q * 8 + k)];
#pragma unroll
        for (int k = 0; k < 8; ++k) gv[k] = g4[lane + 64 * (q * 8 + k)];
#pragma unroll
        for (int k = 0; k < 8; ++k) bv[k] = b4[lane + 64 * (q * 8 + k)];
#pragma unroll
        for (int k = 0; k < 8; ++k) {
            f4 o;
            o.x = gv[k].x * (xv[k].x - mu) * inv + bv[k].x;
            o.y = gv[k].y * (xv[k].y - mu) * inv + bv[k].y;
            o.z = gv[k].z * (xv[k].z - mu) * inv + bv[k].z;
            o.w = gv[k].w * (xv[k].w - mu) * inv + bv[k].w;
            __builtin_nontemporal_store(o, o4 + lane + 64 * (q * 8 + k));
        }
    }
}

extern "C" void kernel_launch(void* const* d_in, const int* in_sizes, int n_in,
                              void* d_out, int out_size, void* d_ws, size_t ws_size,
                              hipStream_t stream) {
    const float* x     = (const float*)d_in[0];
    const float* gamma = (const float*)d_in[1];
    const float* beta  = (const float*)d_in[2];
    const void*  mask  = d_in[3];
    float* out = (float*)d_out;

    float* mg = (float*)d_ws;                      // Fn floats
    unsigned* lwpk = (unsigned*)(mg + Fn);         // 256 uint32

    prep_kernel<<<16, NT, 0, stream>>>(mask, gamma, lwpk, mg);
    dropnorm_kernel<<<Bn / RPB, NT, 0, stream>>>(x, lwpk, mg, beta, out);
}